// Round 4
// baseline (248.175 us; speedup 1.0000x reference)
//
#include <hip/hip_runtime.h>
#include <hip/hip_bf16.h>

#define NTOK 4096   // 64*64 tokens per batch
#define NPOOL 1024  // 32*32 pooled tokens per batch

using short8 = __attribute__((ext_vector_type(8))) short;
using f32x4  = __attribute__((ext_vector_type(4))) float;

__device__ __forceinline__ unsigned short f2bf(float f) {
  __hip_bfloat16 h = __float2bfloat16(f);
  return __builtin_bit_cast(unsigned short, h);
}

// Map local tile row m to a global x row such that rows 4*p..4*p+3 are
// the 2x2 pooling corners of pooled row bx*16+p. (bx in units of 16 pooled rows)
__device__ __forceinline__ int pool_row(int bx, int m) {
  int pg = bx * 16 + (m >> 2);
  int corner = m & 3;
  int batch = pg >> 10;
  int pl = pg & 1023;
  int pi = pl >> 5, pj = pl & 31;
  return (batch << 12) + ((2 * pi + (corner >> 1)) << 6) + 2 * pj + (corner & 1);
}

// Pack weights: wcatT[384][512] = [f(64) | g(64) | h(256)]^T bf16; woT[512][256] bf16.
__global__ __launch_bounds__(256) void pack_w(const float* __restrict__ wf,
                                              const float* __restrict__ wg,
                                              const float* __restrict__ wh,
                                              const float* __restrict__ wo,
                                              unsigned short* __restrict__ wcatT,
                                              unsigned short* __restrict__ woT) {
  int i = blockIdx.x * 256 + threadIdx.x;
  if (i < 384 * 512) {
    int n = i >> 9, k = i & 511;
    float v = (n < 64) ? wf[k * 64 + n]
            : (n < 128) ? wg[k * 64 + (n - 64)]
                        : wh[k * 256 + (n - 128)];
    wcatT[i] = f2bf(v);
  } else if (i < 384 * 512 + 512 * 256) {
    int j = i - 384 * 512;
    int n = j >> 8, k = j & 255;
    woT[j] = f2bf(wo[(size_t)k * 512 + n]);
  }
}

// Fused f/g/h projection, MFMA.
// v2: 8-wave block (512 thr) covers 128 x-rows (pool_row-permuted) x 384 cols.
// Grid 256 (1 block/CU): halves redundant per-CU wcatT staging + barrier count.
__global__ __launch_bounds__(512) void fgh_proj(const float* __restrict__ x,
                                                const unsigned short* __restrict__ wcatT,
                                                unsigned short* __restrict__ fB,
                                                unsigned short* __restrict__ gB,
                                                unsigned short* __restrict__ hT) {
  // staging: As[128][40] @0 (5120) ; Ws[384][40] @5120 (15360) -> 20480 ush
  // epilogue alias: gO[128][72] @0 ; fO[32][72] @9216 ; hO[256][48] @11520 -> 23808 ush
  __shared__ unsigned short lds[23808];
  const int tid = threadIdx.x;
  const int BX = blockIdx.x;
  const int bx2 = BX * 2;  // pool_row() units of 16 pooled rows
  const int wave = tid >> 6, lane = tid & 63;
  const int col = lane & 15, rgrp = lane >> 4;
  const int wrow = (wave >> 2) * 64;   // 0 or 64
  const int wcol = (wave & 3) * 96;    // 0/96/192/288

  f32x4 acc[4][6];
#pragma unroll
  for (int mt = 0; mt < 4; ++mt)
#pragma unroll
    for (int nt = 0; nt < 6; ++nt) acc[mt][nt] = (f32x4){0.f, 0.f, 0.f, 0.f};

  for (int kt = 0; kt < 16; ++kt) {
    __syncthreads();
#pragma unroll
    for (int r = 0; r < 2; ++r) {  // x: 128 rows x 32 k, cvt to bf16
      int idx = tid + r * 512;
      int m = idx >> 3, k4 = (idx & 7) << 2;
      float4 v = *(const float4*)(x + (size_t)pool_row(bx2, m) * 512 + kt * 32 + k4);
      ushort4 o4;
      o4.x = f2bf(v.x); o4.y = f2bf(v.y); o4.z = f2bf(v.z); o4.w = f2bf(v.w);
      *(ushort4*)&lds[m * 40 + k4] = o4;
    }
#pragma unroll
    for (int r = 0; r < 3; ++r) {  // wcatT: 384 n x 32 k
      int idx = tid + r * 512;
      int n = idx >> 2, k8 = (idx & 3) << 3;
      *(uint4*)&lds[5120 + n * 40 + k8] =
          *(const uint4*)(wcatT + (size_t)n * 512 + kt * 32 + k8);
    }
    __syncthreads();

    short8 am[4];
#pragma unroll
    for (int mt = 0; mt < 4; ++mt)
      am[mt] = *(const short8*)&lds[(wrow + mt * 16 + col) * 40 + rgrp * 8];
#pragma unroll
    for (int nt = 0; nt < 6; ++nt) {
      short8 bn = *(const short8*)&lds[5120 + (wcol + nt * 16 + col) * 40 + rgrp * 8];
#pragma unroll
      for (int mt = 0; mt < 4; ++mt)
        acc[mt][nt] = __builtin_amdgcn_mfma_f32_16x16x32_bf16(am[mt], bn, acc[mt][nt], 0, 0, 0);
    }
  }
  __syncthreads();

  // epilogue assembly in LDS (alias over staging)
  unsigned short* gO = lds;           // [128][72]
  unsigned short* fO = lds + 9216;    // [32][72]
  unsigned short* hO = lds + 11520;   // [256][48]
#pragma unroll
  for (int mt = 0; mt < 4; ++mt) {
#pragma unroll
    for (int nt = 0; nt < 6; ++nt) {
      int n = wcol + nt * 16 + col;
      int prl = (wrow >> 2) + mt * 4 + rgrp;  // pooled row 0..31
      f32x4 a = acc[mt][nt];
      if (n < 64) {
        float mx = fmaxf(fmaxf(a[0], a[1]), fmaxf(a[2], a[3]));
        fO[prl * 72 + n] = f2bf(mx);
      } else if (n < 128) {
#pragma unroll
        for (int reg = 0; reg < 4; ++reg)
          gO[(wrow + mt * 16 + rgrp * 4 + reg) * 72 + (n - 64)] = f2bf(a[reg]);
      } else {
        float mx = fmaxf(fmaxf(a[0], a[1]), fmaxf(a[2], a[3]));
        hO[(n - 128) * 48 + prl] = f2bf(mx);
      }
    }
  }
  __syncthreads();

  const int b = BX >> 5, pkb = (BX & 31) * 32;
#pragma unroll
  for (int r = 0; r < 2; ++r) {  // g: 128 rows x 64 ch (rows permuted)
    int idx = tid + r * 512;
    int m = idx >> 3, d8 = (idx & 7) << 3;
    *(uint4*)(gB + (size_t)pool_row(bx2, m) * 64 + d8) = *(const uint4*)&gO[m * 72 + d8];
  }
  if (tid < 256) {               // f: 32 pooled rows x 64 ch
    int pr = tid >> 3, d8 = (tid & 7) << 3;
    *(uint4*)(fB + (size_t)(BX * 32 + pr) * 64 + d8) = *(const uint4*)&fO[pr * 72 + d8];
  }
#pragma unroll
  for (int r = 0; r < 2; ++r) {  // hT: 256 dv x 32 pooled
    int idx = tid + r * 512;
    int dv = idx >> 2, p8 = (idx & 3) << 3;
    *(uint4*)(hT + (((size_t)b * 256 + dv) << 10) + pkb + p8) = *(const uint4*)&hO[dv * 48 + p8];
  }
}

// MFMA flash attention; bf16 output o[32768][256].
// v4 (round-3 WIN form): 8-wave block, 128 q-rows, 256 blocks (1/CU).
__global__ __launch_bounds__(512) void attn_mfma(const __hip_bfloat16* __restrict__ G,
                                                 const __hip_bfloat16* __restrict__ F,
                                                 const __hip_bfloat16* __restrict__ HT,
                                                 unsigned short* __restrict__ O) {
  // staging: fS[64][72] @0 ; hS[256][72] @4608 ; pS[128][72] @23040  (32256 ush)
  // epilogue alias: oS[128][264] @0 (33792 ush = 67584 B total)
  __shared__ unsigned short lds[33792];

  const int tid = threadIdx.x;
  const int wave = tid >> 6, lane = tid & 63;
  const int col = lane & 15;
  const int rgrp = lane >> 4;
  const int b = blockIdx.x >> 5, qt = blockIdx.x & 31;

  const unsigned short* Gb = (const unsigned short*)G + ((size_t)b * NTOK + qt * 128) * 64;
  const unsigned short* Fb = (const unsigned short*)F + (size_t)b * NPOOL * 64;
  const unsigned short* Hb = (const unsigned short*)HT + (size_t)b * 256 * NPOOL;

  // Q fragment straight from global (read once); wave w owns q-rows w*16..w*16+15
  short8 ag[2];
#pragma unroll
  for (int ks = 0; ks < 2; ++ks)
    ag[ks] = *(const short8*)(Gb + (size_t)(wave * 16 + col) * 64 + ks * 32 + rgrp * 8);

  f32x4 oacc[16];
#pragma unroll
  for (int t = 0; t < 16; ++t) oacc[t] = (f32x4){0.f, 0.f, 0.f, 0.f};
  float m_run[4], l_run[4];
#pragma unroll
  for (int r = 0; r < 4; ++r) { m_run[r] = -1e30f; l_run[r] = 0.f; }

  const int fk = tid >> 3, fd8 = (tid & 7) << 3;  // F staging (1 uint4/thread)

  for (int kc = 0; kc < 16; ++kc) {
    __syncthreads();  // previous chunk's LDS reads done
    // F chunk: 64 k-rows x 64 d
    *(uint4*)&lds[fk * 72 + fd8] =
        *(const uint4*)(Fb + (size_t)(kc * 64 + fk) * 64 + fd8);
    // H chunk: 256 dv-rows x 64 k
#pragma unroll
    for (int r = 0; r < 4; ++r) {
      int j = tid + r * 512;
      int dv = j >> 3, k8 = (j & 7) << 3;
      *(uint4*)&lds[4608 + dv * 72 + k8] =
          *(const uint4*)(Hb + (size_t)dv * NPOOL + kc * 64 + k8);
    }
    __syncthreads();  // data ready

    // QK^T
    f32x4 s[4];
#pragma unroll
    for (int t = 0; t < 4; ++t) s[t] = (f32x4){0.f, 0.f, 0.f, 0.f};
#pragma unroll
    for (int ks = 0; ks < 2; ++ks) {
#pragma unroll
      for (int t = 0; t < 4; ++t) {
        short8 bf = *(const short8*)&lds[(t * 16 + col) * 72 + ks * 32 + rgrp * 8];
        s[t] = __builtin_amdgcn_mfma_f32_16x16x32_bf16(ag[ks], bf, s[t], 0, 0, 0);
      }
    }

    // online softmax with exact defer-rescale
    float cm[4];
#pragma unroll
    for (int r = 0; r < 4; ++r) {
      cm[r] = fmaxf(fmaxf(s[0][r], s[1][r]), fmaxf(s[2][r], s[3][r]));
#pragma unroll
      for (int msk = 1; msk < 16; msk <<= 1) cm[r] = fmaxf(cm[r], __shfl_xor(cm[r], msk));
    }
    bool upd = false;
#pragma unroll
    for (int r = 0; r < 4; ++r) upd |= (cm[r] > m_run[r]);
    if (__any(upd)) {
      float alpha[4];
#pragma unroll
      for (int r = 0; r < 4; ++r) {
        float mn = fmaxf(m_run[r], cm[r]);
        alpha[r] = __expf(m_run[r] - mn);
        m_run[r] = mn;
        l_run[r] *= alpha[r];
      }
#pragma unroll
      for (int t = 0; t < 16; ++t) {
#pragma unroll
        for (int r = 0; r < 4; ++r) oacc[t][r] *= alpha[r];
      }
    }

    float rs[4] = {0.f, 0.f, 0.f, 0.f};
    const int prow = wave * 16 + rgrp * 4;
#pragma unroll
    for (int t = 0; t < 4; ++t) {
#pragma unroll
      for (int r = 0; r < 4; ++r) {
        float p = __expf(s[t][r] - m_run[r]);
        rs[r] += p;
        lds[23040 + (prow + r) * 72 + t * 16 + col] = f2bf(p);
      }
    }
#pragma unroll
    for (int r = 0; r < 4; ++r) {
#pragma unroll
      for (int msk = 1; msk < 16; msk <<= 1) rs[r] += __shfl_xor(rs[r], msk);
      l_run[r] += rs[r];
    }

    // PV
    short8 ap[2];
#pragma unroll
    for (int ks = 0; ks < 2; ++ks)
      ap[ks] = *(const short8*)&lds[23040 + (wave * 16 + col) * 72 + ks * 32 + rgrp * 8];
#pragma unroll
    for (int t = 0; t < 16; ++t) {
#pragma unroll
      for (int ks = 0; ks < 2; ++ks) {
        short8 bh = *(const short8*)&lds[4608 + (t * 16 + col) * 72 + ks * 32 + rgrp * 8];
        oacc[t] = __builtin_amdgcn_mfma_f32_16x16x32_bf16(ap[ks], bh, oacc[t], 0, 0, 0);
      }
    }
  }

  // epilogue: normalize, assemble bf16 in LDS (alias), coalesced store
  float inv[4];
#pragma unroll
  for (int r = 0; r < 4; ++r) inv[r] = 1.0f / l_run[r];
  __syncthreads();
  const int qrow = wave * 16 + rgrp * 4;
#pragma unroll
  for (int t = 0; t < 16; ++t) {
#pragma unroll
    for (int r = 0; r < 4; ++r)
      lds[(qrow + r) * 264 + t * 16 + col] = f2bf(oacc[t][r] * inv[r]);
  }
  __syncthreads();
  unsigned short* Ob = O + ((size_t)b * NTOK + qt * 128) * 256;
#pragma unroll
  for (int r = 0; r < 8; ++r) {
    int idx = tid + r * 512;
    int q = idx >> 5, d8 = (idx & 31) << 3;
    *(uint4*)(Ob + (size_t)q * 256 + d8) = *(const uint4*)&lds[q * 264 + d8];
  }
}

// MFMA out-GEMM: out = gamma*(o @ wo) + x. A=o bf16 [32768][256], B=woT[512][256] bf16.
// v2: 8-wave block (512 thr) covers 128 rows x 512 cols, grid 256 (1 block/CU).
// Halves redundant per-CU woT staging + barrier count.
__global__ __launch_bounds__(512) void gemm_out_mfma(const unsigned short* __restrict__ Obf,
                                                     const unsigned short* __restrict__ woT,
                                                     const float* __restrict__ Xres,
                                                     const float* __restrict__ gamma,
                                                     float* __restrict__ Out) {
  __shared__ unsigned short lds[25600];  // As[128][40] @0 ; Ws[512][40] @5120
  const int tid = threadIdx.x;
  const int bx = blockIdx.x;
  const int wave = tid >> 6, lane = tid & 63;
  const int col = lane & 15, rgrp = lane >> 4;
  const int wr = (wave >> 2) * 64;    // 0 or 64
  const int wc = (wave & 3) * 128;    // 0/128/256/384

  f32x4 acc[4][8];
#pragma unroll
  for (int mt = 0; mt < 4; ++mt)
#pragma unroll
    for (int nt = 0; nt < 8; ++nt) acc[mt][nt] = (f32x4){0.f, 0.f, 0.f, 0.f};

  for (int kt = 0; kt < 8; ++kt) {
    __syncthreads();
    {  // A: 128 rows x 32 k (1 uint4/thread)
      int m = tid >> 2, k8 = (tid & 3) << 3;
      *(uint4*)&lds[m * 40 + k8] =
          *(const uint4*)(Obf + ((size_t)bx * 128 + m) * 256 + kt * 32 + k8);
    }
#pragma unroll
    for (int r = 0; r < 4; ++r) {  // B: 512 n x 32 k
      int idx = tid + r * 512;
      int n = idx >> 2, k8 = (idx & 3) << 3;
      *(uint4*)&lds[5120 + n * 40 + k8] =
          *(const uint4*)(woT + (size_t)n * 256 + kt * 32 + k8);
    }
    __syncthreads();

    short8 am[4];
#pragma unroll
    for (int mt = 0; mt < 4; ++mt)
      am[mt] = *(const short8*)&lds[(wr + mt * 16 + col) * 40 + rgrp * 8];
#pragma unroll
    for (int nt = 0; nt < 8; ++nt) {
      short8 bn = *(const short8*)&lds[5120 + (wc + nt * 16 + col) * 40 + rgrp * 8];
#pragma unroll
      for (int mt = 0; mt < 4; ++mt)
        acc[mt][nt] = __builtin_amdgcn_mfma_f32_16x16x32_bf16(am[mt], bn, acc[mt][nt], 0, 0, 0);
    }
  }

  float gm = gamma[0];
#pragma unroll
  for (int mt = 0; mt < 4; ++mt) {
#pragma unroll
    for (int nt = 0; nt < 8; ++nt) {
      int n = wc + nt * 16 + col;
#pragma unroll
      for (int reg = 0; reg < 4; ++reg) {
        size_t row = (size_t)bx * 128 + wr + mt * 16 + rgrp * 4 + reg;
        size_t off = row * 512 + n;
        Out[off] = gm * acc[mt][nt][reg] + Xres[off];
      }
    }
  }
}

extern "C" void kernel_launch(void* const* d_in, const int* in_sizes, int n_in,
                              void* d_out, int out_size, void* d_ws, size_t ws_size,
                              hipStream_t stream) {
  (void)in_sizes; (void)n_in; (void)out_size; (void)ws_size;
  const float* x     = (const float*)d_in[0];
  const float* wf    = (const float*)d_in[1];
  const float* wg    = (const float*)d_in[2];
  const float* wh    = (const float*)d_in[3];
  const float* wo    = (const float*)d_in[4];
  const float* gamma = (const float*)d_in[5];
  float* out = (float*)d_out;

  unsigned short* ws = (unsigned short*)d_ws;
  unsigned short* oB    = ws;               // [32768][256] bf16
  unsigned short* gB    = ws + 8388608;     // [32768][64]
  unsigned short* fB    = ws + 10485760;    // [8192][64]
  unsigned short* hT    = ws + 11010048;    // [8][256][1024]
  unsigned short* wcatT = ws + 13107200;    // [384][512]
  unsigned short* woT   = ws + 13303808;    // [512][256]

  pack_w<<<1280, dim3(256), 0, stream>>>(wf, wg, wh, wo, wcatT, woT);
  fgh_proj<<<256, dim3(512), 0, stream>>>(x, wcatT, fB, gB, hT);
  attn_mfma<<<256, dim3(512), 0, stream>>>((const __hip_bfloat16*)gB, (const __hip_bfloat16*)fB,
                                           (const __hip_bfloat16*)hT, oB);
  gemm_out_mfma<<<256, dim3(512), 0, stream>>>(oB, woT, x, gamma, out);
}

// Round 5
// 225.972 us; speedup vs baseline: 1.0983x; 1.0983x over previous
//
#include <hip/hip_runtime.h>
#include <hip/hip_bf16.h>

#define NTOK 4096   // 64*64 tokens per batch
#define NPOOL 1024  // 32*32 pooled tokens per batch

using short8 = __attribute__((ext_vector_type(8))) short;
using f32x4  = __attribute__((ext_vector_type(4))) float;

__device__ __forceinline__ unsigned short f2bf(float f) {
  __hip_bfloat16 h = __float2bfloat16(f);
  return __builtin_bit_cast(unsigned short, h);
}

// Map local tile row m (0..63) to a global x row such that rows 4*p..4*p+3 are
// the 2x2 pooling corners of pooled row bx*16+p.
__device__ __forceinline__ int pool_row(int bx, int m) {
  int pg = bx * 16 + (m >> 2);
  int corner = m & 3;
  int batch = pg >> 10;
  int pl = pg & 1023;
  int pi = pl >> 5, pj = pl & 31;
  return (batch << 12) + ((2 * pi + (corner >> 1)) << 6) + 2 * pj + (corner & 1);
}

// Pack weights: wcatT[384][512] = [f(64) | g(64) | h(256)]^T bf16; woT[512][256] bf16.
__global__ __launch_bounds__(256) void pack_w(const float* __restrict__ wf,
                                              const float* __restrict__ wg,
                                              const float* __restrict__ wh,
                                              const float* __restrict__ wo,
                                              unsigned short* __restrict__ wcatT,
                                              unsigned short* __restrict__ woT) {
  int i = blockIdx.x * 256 + threadIdx.x;
  if (i < 384 * 512) {
    int n = i >> 9, k = i & 511;
    float v = (n < 64) ? wf[k * 64 + n]
            : (n < 128) ? wg[k * 64 + (n - 64)]
                        : wh[k * 256 + (n - 128)];
    wcatT[i] = f2bf(v);
  } else if (i < 384 * 512 + 512 * 256) {
    int j = i - 384 * 512;
    int n = j >> 8, k = j & 255;
    woT[j] = f2bf(wo[(size_t)k * 512 + n]);
  }
}

// Fused f/g/h projection, MFMA.
// v3: 512 threads / 8 waves per block, block tile 64 rows x 384 cols
// (wave tile 64x48). Grid 512 -> 2 blocks/CU (two independent barrier
// domains) AND 4 waves/SIMD (vs round-0's 2): staging latency of one block
// hides under the other block's compute.
__global__ __launch_bounds__(512) void fgh_proj(const float* __restrict__ x,
                                                const unsigned short* __restrict__ wcatT,
                                                unsigned short* __restrict__ fB,
                                                unsigned short* __restrict__ gB,
                                                unsigned short* __restrict__ hT) {
  __shared__ unsigned short lds[17920];  // As[64][40] @0 ; WsT[384][40] @2560
  const int tid = threadIdx.x;
  const int bx = blockIdx.x;
  const int wave = tid >> 6, lane = tid & 63;
  const int col = lane & 15, rgrp = lane >> 4;
  const int wcol = wave * 48;

  f32x4 acc[4][3];
#pragma unroll
  for (int mt = 0; mt < 4; ++mt)
#pragma unroll
    for (int nt = 0; nt < 3; ++nt) acc[mt][nt] = (f32x4){0.f, 0.f, 0.f, 0.f};

  for (int kt = 0; kt < 16; ++kt) {
    __syncthreads();
    {  // x: 64 rows x 32 k, cvt to bf16 (512 float4, 1/thread)
      int m = tid >> 3, k4 = (tid & 7) << 2;
      float4 v = *(const float4*)(x + (size_t)pool_row(bx, m) * 512 + kt * 32 + k4);
      ushort4 o4;
      o4.x = f2bf(v.x); o4.y = f2bf(v.y); o4.z = f2bf(v.z); o4.w = f2bf(v.w);
      *(ushort4*)&lds[m * 40 + k4] = o4;
    }
#pragma unroll
    for (int r = 0; r < 3; ++r) {  // wcatT: 384 n x 32 k (1536 uint4, 3/thread)
      int idx = tid + r * 512;
      int n = idx >> 2, k8 = (idx & 3) << 3;
      *(uint4*)&lds[2560 + n * 40 + k8] =
          *(const uint4*)(wcatT + (size_t)n * 512 + kt * 32 + k8);
    }
    __syncthreads();

    short8 am[4];
#pragma unroll
    for (int mt = 0; mt < 4; ++mt)
      am[mt] = *(const short8*)&lds[(mt * 16 + col) * 40 + rgrp * 8];
#pragma unroll
    for (int nt = 0; nt < 3; ++nt) {
      short8 bn = *(const short8*)&lds[2560 + (wcol + nt * 16 + col) * 40 + rgrp * 8];
#pragma unroll
      for (int mt = 0; mt < 4; ++mt)
        acc[mt][nt] = __builtin_amdgcn_mfma_f32_16x16x32_bf16(am[mt], bn, acc[mt][nt], 0, 0, 0);
    }
  }
  __syncthreads();

  // epilogue assembly in LDS (alias over staging)
  unsigned short* gO = lds;          // [64][72]
  unsigned short* fO = lds + 4608;   // [16][72]
  unsigned short* hO = lds + 5760;   // [256][24]
#pragma unroll
  for (int mt = 0; mt < 4; ++mt) {
#pragma unroll
    for (int nt = 0; nt < 3; ++nt) {
      int n = wcol + nt * 16 + col;
      f32x4 a = acc[mt][nt];
      if (n < 64) {
        float mx = fmaxf(fmaxf(a[0], a[1]), fmaxf(a[2], a[3]));
        fO[(mt * 4 + rgrp) * 72 + n] = f2bf(mx);
      } else if (n < 128) {
#pragma unroll
        for (int reg = 0; reg < 4; ++reg)
          gO[(mt * 16 + rgrp * 4 + reg) * 72 + (n - 64)] = f2bf(a[reg]);
      } else {
        float mx = fmaxf(fmaxf(a[0], a[1]), fmaxf(a[2], a[3]));
        hO[(n - 128) * 24 + (mt * 4 + rgrp)] = f2bf(mx);
      }
    }
  }
  __syncthreads();

  const int b = bx >> 6, pkb = (bx & 63) * 16;
  {  // g: 64 rows x 64 ch (rows permuted), 512 uint4, 1/thread
    int m = tid >> 3, d8 = (tid & 7) << 3;
    *(uint4*)(gB + (size_t)pool_row(bx, m) * 64 + d8) = *(const uint4*)&gO[m * 72 + d8];
  }
  if (tid < 128) {  // f: 16 pooled rows x 64 ch
    int pr = tid >> 3, d8 = (tid & 7) << 3;
    *(uint4*)(fB + (size_t)(bx * 16 + pr) * 64 + d8) = *(const uint4*)&fO[pr * 72 + d8];
  }
  {  // hT: 256 dv x 16 pooled, 512 uint4, 1/thread
    int dv = tid >> 1, p8 = (tid & 1) << 3;
    *(uint4*)(hT + (((size_t)b * 256 + dv) << 10) + pkb + p8) = *(const uint4*)&hO[dv * 24 + p8];
  }
}

// MFMA flash attention; bf16 output o[32768][256].
// v4 (round-3 WIN form, unchanged): 8-wave block, 128 q-rows, 256 blocks (1/CU).
__global__ __launch_bounds__(512) void attn_mfma(const __hip_bfloat16* __restrict__ G,
                                                 const __hip_bfloat16* __restrict__ F,
                                                 const __hip_bfloat16* __restrict__ HT,
                                                 unsigned short* __restrict__ O) {
  // staging: fS[64][72] @0 ; hS[256][72] @4608 ; pS[128][72] @23040  (32256 ush)
  // epilogue alias: oS[128][264] @0 (33792 ush = 67584 B total)
  __shared__ unsigned short lds[33792];

  const int tid = threadIdx.x;
  const int wave = tid >> 6, lane = tid & 63;
  const int col = lane & 15;
  const int rgrp = lane >> 4;
  const int b = blockIdx.x >> 5, qt = blockIdx.x & 31;

  const unsigned short* Gb = (const unsigned short*)G + ((size_t)b * NTOK + qt * 128) * 64;
  const unsigned short* Fb = (const unsigned short*)F + (size_t)b * NPOOL * 64;
  const unsigned short* Hb = (const unsigned short*)HT + (size_t)b * 256 * NPOOL;

  // Q fragment straight from global (read once); wave w owns q-rows w*16..w*16+15
  short8 ag[2];
#pragma unroll
  for (int ks = 0; ks < 2; ++ks)
    ag[ks] = *(const short8*)(Gb + (size_t)(wave * 16 + col) * 64 + ks * 32 + rgrp * 8);

  f32x4 oacc[16];
#pragma unroll
  for (int t = 0; t < 16; ++t) oacc[t] = (f32x4){0.f, 0.f, 0.f, 0.f};
  float m_run[4], l_run[4];
#pragma unroll
  for (int r = 0; r < 4; ++r) { m_run[r] = -1e30f; l_run[r] = 0.f; }

  const int fk = tid >> 3, fd8 = (tid & 7) << 3;  // F staging (1 uint4/thread)

  for (int kc = 0; kc < 16; ++kc) {
    __syncthreads();  // previous chunk's LDS reads done
    // F chunk: 64 k-rows x 64 d
    *(uint4*)&lds[fk * 72 + fd8] =
        *(const uint4*)(Fb + (size_t)(kc * 64 + fk) * 64 + fd8);
    // H chunk: 256 dv-rows x 64 k
#pragma unroll
    for (int r = 0; r < 4; ++r) {
      int j = tid + r * 512;
      int dv = j >> 3, k8 = (j & 7) << 3;
      *(uint4*)&lds[4608 + dv * 72 + k8] =
          *(const uint4*)(Hb + (size_t)dv * NPOOL + kc * 64 + k8);
    }
    __syncthreads();  // data ready

    // QK^T
    f32x4 s[4];
#pragma unroll
    for (int t = 0; t < 4; ++t) s[t] = (f32x4){0.f, 0.f, 0.f, 0.f};
#pragma unroll
    for (int ks = 0; ks < 2; ++ks) {
#pragma unroll
      for (int t = 0; t < 4; ++t) {
        short8 bf = *(const short8*)&lds[(t * 16 + col) * 72 + ks * 32 + rgrp * 8];
        s[t] = __builtin_amdgcn_mfma_f32_16x16x32_bf16(ag[ks], bf, s[t], 0, 0, 0);
      }
    }

    // online softmax with exact defer-rescale
    float cm[4];
#pragma unroll
    for (int r = 0; r < 4; ++r) {
      cm[r] = fmaxf(fmaxf(s[0][r], s[1][r]), fmaxf(s[2][r], s[3][r]));
#pragma unroll
      for (int msk = 1; msk < 16; msk <<= 1) cm[r] = fmaxf(cm[r], __shfl_xor(cm[r], msk));
    }
    bool upd = false;
#pragma unroll
    for (int r = 0; r < 4; ++r) upd |= (cm[r] > m_run[r]);
    if (__any(upd)) {
      float alpha[4];
#pragma unroll
      for (int r = 0; r < 4; ++r) {
        float mn = fmaxf(m_run[r], cm[r]);
        alpha[r] = __expf(m_run[r] - mn);
        m_run[r] = mn;
        l_run[r] *= alpha[r];
      }
#pragma unroll
      for (int t = 0; t < 16; ++t) {
#pragma unroll
        for (int r = 0; r < 4; ++r) oacc[t][r] *= alpha[r];
      }
    }

    float rs[4] = {0.f, 0.f, 0.f, 0.f};
    const int prow = wave * 16 + rgrp * 4;
#pragma unroll
    for (int t = 0; t < 4; ++t) {
#pragma unroll
      for (int r = 0; r < 4; ++r) {
        float p = __expf(s[t][r] - m_run[r]);
        rs[r] += p;
        lds[23040 + (prow + r) * 72 + t * 16 + col] = f2bf(p);
      }
    }
#pragma unroll
    for (int r = 0; r < 4; ++r) {
#pragma unroll
      for (int msk = 1; msk < 16; msk <<= 1) rs[r] += __shfl_xor(rs[r], msk);
      l_run[r] += rs[r];
    }

    // PV
    short8 ap[2];
#pragma unroll
    for (int ks = 0; ks < 2; ++ks)
      ap[ks] = *(const short8*)&lds[23040 + (wave * 16 + col) * 72 + ks * 32 + rgrp * 8];
#pragma unroll
    for (int t = 0; t < 16; ++t) {
#pragma unroll
      for (int ks = 0; ks < 2; ++ks) {
        short8 bh = *(const short8*)&lds[4608 + (t * 16 + col) * 72 + ks * 32 + rgrp * 8];
        oacc[t] = __builtin_amdgcn_mfma_f32_16x16x32_bf16(ap[ks], bh, oacc[t], 0, 0, 0);
      }
    }
  }

  // epilogue: normalize, assemble bf16 in LDS (alias), coalesced store
  float inv[4];
#pragma unroll
  for (int r = 0; r < 4; ++r) inv[r] = 1.0f / l_run[r];
  __syncthreads();
  const int qrow = wave * 16 + rgrp * 4;
#pragma unroll
  for (int t = 0; t < 16; ++t) {
#pragma unroll
    for (int r = 0; r < 4; ++r)
      lds[(qrow + r) * 264 + t * 16 + col] = f2bf(oacc[t][r] * inv[r]);
  }
  __syncthreads();
  unsigned short* Ob = O + ((size_t)b * NTOK + qt * 128) * 256;
#pragma unroll
  for (int r = 0; r < 8; ++r) {
    int idx = tid + r * 512;
    int q = idx >> 5, d8 = (idx & 31) << 3;
    *(uint4*)(Ob + (size_t)q * 256 + d8) = *(const uint4*)&lds[q * 264 + d8];
  }
}

// MFMA out-GEMM: out = gamma*(o @ wo) + x. A=o bf16 [32768][256], B=woT[512][256] bf16.
// v3: 512 threads / 8 waves, block tile 64 rows x 512 cols (wave tile 64x64).
// Grid 512 -> 2 blocks/CU, 4 waves/SIMD.
__global__ __launch_bounds__(512) void gemm_out_mfma(const unsigned short* __restrict__ Obf,
                                                     const unsigned short* __restrict__ woT,
                                                     const float* __restrict__ Xres,
                                                     const float* __restrict__ gamma,
                                                     float* __restrict__ Out) {
  __shared__ unsigned short lds[23040];  // As[64][40] @0 ; WsT[512][40] @2560
  const int tid = threadIdx.x;
  const int bx = blockIdx.x;
  const int wave = tid >> 6, lane = tid & 63;
  const int col = lane & 15, rgrp = lane >> 4;
  const int wc = wave * 64;

  f32x4 acc[4][4];
#pragma unroll
  for (int mt = 0; mt < 4; ++mt)
#pragma unroll
    for (int nt = 0; nt < 4; ++nt) acc[mt][nt] = (f32x4){0.f, 0.f, 0.f, 0.f};

  for (int kt = 0; kt < 8; ++kt) {
    __syncthreads();
    if (tid < 256) {  // A: 64 rows x 32 k (256 uint4)
      int m = tid >> 2, k8 = (tid & 3) << 3;
      *(uint4*)&lds[m * 40 + k8] =
          *(const uint4*)(Obf + ((size_t)bx * 64 + m) * 256 + kt * 32 + k8);
    }
#pragma unroll
    for (int r = 0; r < 4; ++r) {  // B: 512 n x 32 k (2048 uint4, 4/thread)
      int idx = tid + r * 512;
      int n = idx >> 2, k8 = (idx & 3) << 3;
      *(uint4*)&lds[2560 + n * 40 + k8] =
          *(const uint4*)(woT + (size_t)n * 256 + kt * 32 + k8);
    }
    __syncthreads();

    short8 am[4];
#pragma unroll
    for (int mt = 0; mt < 4; ++mt)
      am[mt] = *(const short8*)&lds[(mt * 16 + col) * 40 + rgrp * 8];
#pragma unroll
    for (int nt = 0; nt < 4; ++nt) {
      short8 bn = *(const short8*)&lds[2560 + (wc + nt * 16 + col) * 40 + rgrp * 8];
#pragma unroll
      for (int mt = 0; mt < 4; ++mt)
        acc[mt][nt] = __builtin_amdgcn_mfma_f32_16x16x32_bf16(am[mt], bn, acc[mt][nt], 0, 0, 0);
    }
  }

  float gm = gamma[0];
#pragma unroll
  for (int mt = 0; mt < 4; ++mt) {
#pragma unroll
    for (int nt = 0; nt < 4; ++nt) {
      int n = wc + nt * 16 + col;
#pragma unroll
      for (int reg = 0; reg < 4; ++reg) {
        size_t row = (size_t)bx * 64 + mt * 16 + rgrp * 4 + reg;
        size_t off = row * 512 + n;
        Out[off] = gm * acc[mt][nt][reg] + Xres[off];
      }
    }
  }
}

extern "C" void kernel_launch(void* const* d_in, const int* in_sizes, int n_in,
                              void* d_out, int out_size, void* d_ws, size_t ws_size,
                              hipStream_t stream) {
  (void)in_sizes; (void)n_in; (void)out_size; (void)ws_size;
  const float* x     = (const float*)d_in[0];
  const float* wf    = (const float*)d_in[1];
  const float* wg    = (const float*)d_in[2];
  const float* wh    = (const float*)d_in[3];
  const float* wo    = (const float*)d_in[4];
  const float* gamma = (const float*)d_in[5];
  float* out = (float*)d_out;

  unsigned short* ws = (unsigned short*)d_ws;
  unsigned short* oB    = ws;               // [32768][256] bf16
  unsigned short* gB    = ws + 8388608;     // [32768][64]
  unsigned short* fB    = ws + 10485760;    // [8192][64]
  unsigned short* hT    = ws + 11010048;    // [8][256][1024]
  unsigned short* wcatT = ws + 13107200;    // [384][512]
  unsigned short* woT   = ws + 13303808;    // [512][256]

  pack_w<<<1280, dim3(256), 0, stream>>>(wf, wg, wh, wo, wcatT, woT);
  fgh_proj<<<512, dim3(512), 0, stream>>>(x, wcatT, fB, gB, hT);
  attn_mfma<<<256, dim3(512), 0, stream>>>((const __hip_bfloat16*)gB, (const __hip_bfloat16*)fB,
                                           (const __hip_bfloat16*)hT, oB);
  gemm_out_mfma<<<512, dim3(512), 0, stream>>>(oB, woT, x, gamma, out);
}